// Round 5
// baseline (372.748 us; speedup 1.0000x reference)
//
#include <hip/hip_runtime.h>
#include <hip/hip_bf16.h>

#define B_  2
#define T_  2048
#define D_  1024
#define H_  16
#define DH_ 64
#define M_  (B_*T_)   // 4096

typedef _Float16 f16;
typedef __attribute__((ext_vector_type(4))) _Float16 f16x4;
typedef __attribute__((ext_vector_type(8))) _Float16 f16x8;
typedef __attribute__((ext_vector_type(4))) float f32x4;

// async global->LDS, 16B per lane; LDS dest must be wave-uniform-base + lane*16
#define GLOAD_LDS(gp, lp) __builtin_amdgcn_global_load_lds( \
    (const __attribute__((address_space(1))) void*)(gp),    \
    (__attribute__((address_space(3))) void*)(lp), 16, 0, 0)

// ---------------- prep: x fp32->fp16 convert + 4 weight transposes, one launch ----------------
__global__ void prep(const float* __restrict__ x,
                     const float* __restrict__ wq, const float* __restrict__ wk,
                     const float* __restrict__ wv, const float* __restrict__ wo,
                     f16* __restrict__ xb, f16* __restrict__ wqkvT, f16* __restrict__ woutT) {
  __shared__ float tile[32][33];
  const int bid = blockIdx.x;
  if (bid < 2048) {
    size_t i = ((size_t)bid * 256 + threadIdx.x) * 8;
    float4 a = *(const float4*)(x + i);
    float4 b = *(const float4*)(x + i + 4);
    f16x8 o;
    o[0]=(f16)a.x; o[1]=(f16)a.y; o[2]=(f16)a.z; o[3]=(f16)a.w;
    o[4]=(f16)b.x; o[5]=(f16)b.y; o[6]=(f16)b.z; o[7]=(f16)b.w;
    *(f16x8*)(xb + i) = o;
  } else {
    const int b2 = bid - 2048;
    const int j = b2 >> 10, rem = b2 & 1023;
    const float* src = (j==0)?wq:(j==1)?wk:(j==2)?wv:wo;
    f16* dst = (j<3) ? (wqkvT + (size_t)j*D_*D_) : woutT;
    const int n0 = (rem & 31)*32, k0 = (rem >> 5)*32;
    const int tx = threadIdx.x & 31, ty = threadIdx.x >> 5;  // (32,8)
    #pragma unroll
    for (int i=0;i<32;i+=8)
      tile[ty+i][tx] = src[(size_t)(k0+ty+i)*D_ + n0+tx];
    __syncthreads();
    #pragma unroll
    for (int i=0;i<32;i+=8)
      dst[(size_t)(n0+ty+i)*D_ + k0+tx] = (f16)tile[tx][ty+i];
  }
}

// ---------------- QKV projection GEMM v2: 256x256 tile, 8 waves, BK=32, fused N=3072 ----------
// grid 192 = 16 m-blocks x 12 fused-n blocks (j = nf>>2). 512 threads = 8 waves (2M x 4N),
// per-wave output 128x64 (acc 4x8 f32x4 = 128 VGPR). LDS 64 KB (A/B dbuf, 256x32 each),
// logical 32-f16 rows folded 2:1 into 128B physical rows with the proven XOR-16B-block swizzle.
// Per K-tile per wave: 12 ds_read_b128 + 32 MFMA; one vmcnt(0)+barrier per tile (compute span
// ~2x load latency at 2 blocks/CU -> drain is cheap by arithmetic).
__launch_bounds__(512, 2)
__global__ void qkv_gemm(const f16* __restrict__ xb, const f16* __restrict__ wT,
                         f16* __restrict__ Qp, f16* __restrict__ Kp, f16* __restrict__ Vtp) {
  const int fid = blockIdx.x;              // [0,192)
  const int mb = fid & 15, nf = fid >> 4;  // nf in [0,12)
  const int m0 = mb * 256;
  const int n0f = nf * 256;
  const int j  = n0f >> 10;                // 0..2 (Q,K,V)
  const int n0 = n0f & 1023;               // within-matrix feature offset
  const f16* A0 = xb + (size_t)m0*D_;
  const f16* B0 = wT + (size_t)j*D_*D_ + (size_t)n0*D_;
  __shared__ alignas(16) f16 smem[4*256*32];   // As[2][8192] | Bs[2][8192] = 64 KB
  f16* As = smem;
  f16* Bs = smem + 2*256*32;
  const int tid = threadIdx.x;             // 512
  const int lane = tid & 63, wave = tid >> 6;
  const int ln = lane & 15, quad = lane >> 4;
  const int wm = wave >> 2, wn = wave & 3; // 2 x 4 wave grid

  const bool swapped = (j < 2);

  f32x4 acc[4][8];
  #pragma unroll
  for (int a=0;a<4;++a)
    #pragma unroll
    for (int b=0;b<8;++b) acc[a][b] = f32x4{0.f,0.f,0.f,0.f};

  // stage K-tile tt (cols tt*32..+32) of A and B into dbuf slot bi.
  // physical layout: 128 rows x 128B; logical row r, col-block cb (0..3) at
  // phys_row = r>>1, phys_blk = (((r&1)<<2)|cb) ^ (phys_row&7).
  // staging writes linear phys slots; source address carries the inverse swizzle.
  #define STAGE(tt, bi) do {                                                  \
    const int k0_ = (tt)*32;                                                  \
    _Pragma("unroll")                                                         \
    for (int p_ = 0; p_ < 2; ++p_) {                                          \
      int slot_ = p_*512 + tid;                                               \
      int pr_ = slot_ >> 3, pb_ = slot_ & 7;                                  \
      int ob_ = pb_ ^ (pr_ & 7);                                              \
      int r_  = pr_*2 + (ob_ >> 2);                                           \
      int cb_ = ob_ & 3;                                                      \
      GLOAD_LDS(A0 + (size_t)r_*D_ + k0_ + cb_*8,                             \
                As + (size_t)(bi)*8192 + (size_t)slot_*8);                    \
      GLOAD_LDS(B0 + (size_t)r_*D_ + k0_ + cb_*8,                             \
                Bs + (size_t)(bi)*8192 + (size_t)slot_*8);                    \
    }                                                                         \
  } while (0)

  STAGE(0, 0);

  for (int t = 0; t < 32; ++t) {
    asm volatile("s_waitcnt vmcnt(0)" ::: "memory");
    __builtin_amdgcn_s_barrier();
    if (t < 31) STAGE(t + 1, (t + 1) & 1);   // issued after barrier: WAR-safe vs lagging waves

    const f16* Ac = As + (size_t)(t & 1)*8192;
    const f16* Bc = Bs + (size_t)(t & 1)*8192;

    // frag read: logical row r, k-block quad -> swizzled phys addr
    f16x8 af[8], bf[4];
    #pragma unroll
    for (int mt = 0; mt < 8; ++mt) {
      int r  = wm*128 + mt*16 + ln;
      int pr = r >> 1;
      int pb = (((r & 1) << 2) | quad) ^ (pr & 7);
      af[mt] = *(const f16x8*)(Ac + (size_t)pr*64 + pb*8);
    }
    #pragma unroll
    for (int nt = 0; nt < 4; ++nt) {
      int r  = wn*64 + nt*16 + ln;
      int pr = r >> 1;
      int pb = (((r & 1) << 2) | quad) ^ (pr & 7);
      bf[nt] = *(const f16x8*)(Bc + (size_t)pr*64 + pb*8);
    }

    __builtin_amdgcn_s_setprio(1);
    if (swapped) {
      #pragma unroll
      for (int nt = 0; nt < 4; ++nt)
        #pragma unroll
        for (int mt = 0; mt < 8; ++mt)
          acc[nt][mt] = __builtin_amdgcn_mfma_f32_16x16x32_f16(bf[nt], af[mt], acc[nt][mt], 0, 0, 0);
    } else {
      #pragma unroll
      for (int nt = 0; nt < 4; ++nt)
        #pragma unroll
        for (int mt = 0; mt < 8; ++mt)
          acc[nt][mt] = __builtin_amdgcn_mfma_f32_16x16x32_f16(af[mt], bf[nt], acc[nt][mt], 0, 0, 0);
    }
    __builtin_amdgcn_s_setprio(0);
  }
  #undef STAGE

  if (swapped) {
    // C^T fragments: row n = wn*64+nt*16+quad*4+rr (feature), col m = wm*128+mt*16+ln (token)
    const float scale = (j == 0) ? (0.125f * 1.44269504088896f) : 1.0f;
    f16* dstB = (j == 0) ? Qp : Kp;
    #pragma unroll
    for (int nt = 0; nt < 4; ++nt)
      #pragma unroll
      for (int mt = 0; mt < 8; ++mt) {
        int gm  = m0 + wm*128 + mt*16 + ln;          // token
        int gnl = n0 + wn*64 + nt*16 + quad*4;       // feature (base of 4)
        int bb = gm >> 11, tt = gm & (T_-1);
        int h  = gnl >> 6, dd = gnl & (DH_-1);
        f16x4 v;
        #pragma unroll
        for (int rr = 0; rr < 4; ++rr) v[rr] = (f16)(acc[nt][mt][rr] * scale);
        *(f16x4*)&dstB[((((size_t)bb*H_ + h)*T_ + tt)*DH_) + dd] = v;
      }
  } else {
    // V, C fragments: row m = wm*128+mt*16+quad*4+rr (token, 4 consecutive), col n = feature
    // -> direct f16x4 stores into Vt[b,h,d,t] (4 consecutive t at fixed d)
    #pragma unroll
    for (int nt = 0; nt < 4; ++nt)
      #pragma unroll
      for (int mt = 0; mt < 8; ++mt) {
        int gm  = m0 + wm*128 + mt*16 + quad*4;      // token base (4 consecutive)
        int gnl = n0 + wn*64 + nt*16 + ln;           // feature
        int bb = gm >> 11, tt = gm & (T_-1);
        int h  = gnl >> 6, dd = gnl & (DH_-1);
        f16x4 v;
        v[0]=(f16)acc[nt][mt][0]; v[1]=(f16)acc[nt][mt][1];
        v[2]=(f16)acc[nt][mt][2]; v[3]=(f16)acc[nt][mt][3];
        *(f16x4*)&Vtp[((size_t)(bb*H_ + h)*DH_ + dd)*T_ + tt] = v;
      }
  }
}

// ---------------- flash attention v3: kv-split waves, in-register P ----------------
// grid 1024: bh = fid & 31 (same head -> same XCD), qt = 31 - (fid >> 5) (heavy first).
// Block owns ONE 64-row q-tile; wave w owns kv rows [w*16, w*16+16) of each staged tile.
// All 64 q rows in registers (qf[4][2]). S^T fragment (kv=quad*4+rr, q=ln) is EXACTLY the
// B-operand fragment of mfma_f32_16x16x16f16 -> P never touches LDS or lanes.
__launch_bounds__(256, 3)
__global__ void flash(const f16* __restrict__ Qp, const f16* __restrict__ Kp,
                      const f16* __restrict__ Vtp, f16* __restrict__ ctx) {
  const int fid = blockIdx.x;
  const int bh = fid & 31;
  const int qt = 31 - (fid >> 5);       // heavy first
  const int b = bh >> 4, h = bh & (H_-1);
  const f16* Kh = Kp  + (size_t)bh * T_ * DH_;
  const f16* Vh = Vtp + (size_t)bh * DH_ * T_;
  const f16* Qh = Qp  + (size_t)bh * T_ * DH_;
  const int tid = threadIdx.x, lane = tid & 63, w = tid >> 6;
  const int ln = lane & 15, quad = lane >> 4;

  __shared__ alignas(16) char smem[32768];
  f16* Ks = (f16*)smem;            // [2][64][64], XOR-swizzled 16B blocks
  f16* Vs = (f16*)(smem + 16384);  // [2][64][64] (V^T rows d), same swizzle

  // Q fragments: all 64 q rows (4 groups of 16) per wave
  f16x8 qf[4][2];
  #pragma unroll
  for (int g = 0; g < 4; ++g)
    #pragma unroll
    for (int ks = 0; ks < 2; ++ks)
      qf[g][ks] = *(const f16x8*)&Qh[(size_t)(qt*64 + g*16 + ln)*DH_ + ks*32 + quad*8];

  f32x4 o[4][4];   // [dt][g]: O^T[d=dt*16+quad*4+rr][q=g*16+ln] partial over wave's kv
  #pragma unroll
  for (int dt = 0; dt < 4; ++dt)
    #pragma unroll
    for (int g = 0; g < 4; ++g) o[dt][g] = f32x4{0.f,0.f,0.f,0.f};
  float lp[4] = {0.f, 0.f, 0.f, 0.f};

  // prologue: stage kv tile 0 into buffer 0
  #pragma unroll
  for (int i = 0; i < 2; ++i) {
    int slot = i*256 + tid;
    int row  = slot >> 3;
    int c    = (slot & 7) ^ (row & 7);
    GLOAD_LDS(Kh + (size_t)row*DH_ + c*8, Ks + (size_t)slot*8);
    GLOAD_LDS(Vh + (size_t)row*T_  + c*8, Vs + (size_t)slot*8);
  }
  __syncthreads();

  for (int it = 0; it <= qt; ++it) {
    const f16* Kc = Ks + (it & 1)*4096;
    const f16* Vc = Vs + (it & 1)*4096;
    if (it < qt) {    // async-prefetch next tile into other buffer
      const int kv1 = (it + 1)*64;
      f16* Kn = Ks + ((it + 1) & 1)*4096;
      f16* Vn = Vs + ((it + 1) & 1)*4096;
      #pragma unroll
      for (int i = 0; i < 2; ++i) {
        int slot = i*256 + tid;
        int row  = slot >> 3;
        int c    = (slot & 7) ^ (row & 7);
        GLOAD_LDS(Kh + (size_t)(kv1 + row)*DH_ + c*8, Kn + (size_t)slot*8);
        GLOAD_LDS(Vh + (size_t)row*T_ + kv1 + c*8,    Vn + (size_t)slot*8);
      }
    }

    // QK^T: s[g] = S^T[kv = w*16+quad*4+rr][q = g*16+ln]
    f32x4 s[4];
    #pragma unroll
    for (int g = 0; g < 4; ++g) s[g] = f32x4{0.f,0.f,0.f,0.f};
    #pragma unroll
    for (int ks = 0; ks < 2; ++ks) {
      f16x8 kx = *(const f16x8*)(Kc + (size_t)(w*16 + ln)*64 + (((ks*4 + quad) ^ (ln & 7))*8));
      #pragma unroll
      for (int g = 0; g < 4; ++g)
        s[g] = __builtin_amdgcn_mfma_f32_16x16x32_f16(kx, qf[g][ks], s[g], 0, 0, 0);
    }

    if (it == qt) {    // diagonal tile: causal mask (kv_local > q_local)
      #pragma unroll
      for (int g = 0; g < 4; ++g)
        #pragma unroll
        for (int rr = 0; rr < 4; ++rr)
          if (w*16 + quad*4 + rr > g*16 + ln) s[g][rr] = -INFINITY;
    }

    // exp2 (Q pre-scaled by log2e) + pack to f16 + denominator partials
    f16x4 pb[4];
    #pragma unroll
    for (int g = 0; g < 4; ++g) {
      #pragma unroll
      for (int rr = 0; rr < 4; ++rr) {
        float pe = __builtin_amdgcn_exp2f(s[g][rr]);
        lp[g] += pe;
        pb[g][rr] = (f16)pe;
      }
    }

    // PV partial: o[dt][g] += V^T[d][kv-slice] * P^T[kv-slice][q], k=16 MFMA
    #pragma unroll
    for (int dt = 0; dt < 4; ++dt) {
      f16x4 vf = *(const f16x4*)(Vc + (size_t)(dt*16 + ln)*64
                   + (((2*w + (quad >> 1)) ^ (ln & 7))*8) + (quad & 1)*4);
      #pragma unroll
      for (int g = 0; g < 4; ++g)
        o[dt][g] = __builtin_amdgcn_mfma_f32_16x16x16f16(vf, pb[g], o[dt][g], 0, 0, 0);
    }
    __syncthreads();   // drains vmcnt(0): prefetched tile complete; bufs safe to swap
  }

  // quad-reduce denominator partials (each lane's lp covers its quad's 4 kv rows)
  #pragma unroll
  for (int g = 0; g < 4; ++g) {
    lp[g] += __shfl_xor(lp[g], 16, 64);
    lp[g] += __shfl_xor(lp[g], 32, 64);
  }

  // cross-wave reduction tree in LDS (reuse Ks/Vs region): buf[65][68] f32 (O^T rows 0..63, l row 64)
  float* buf = (float*)smem;
  #define WR_PART() do {                                                        \
    _Pragma("unroll")                                                           \
    for (int dt = 0; dt < 4; ++dt)                                              \
      _Pragma("unroll")                                                         \
      for (int g = 0; g < 4; ++g)                                               \
        *(f32x4*)&buf[(size_t)(g*16 + ln)*68 + dt*16 + quad*4] = o[dt][g];      \
    if (quad == 0) {                                                            \
      _Pragma("unroll")                                                         \
      for (int g = 0; g < 4; ++g) buf[64*68 + g*16 + ln] = lp[g];               \
    }                                                                           \
  } while (0)
  #define ACC_PART() do {                                                       \
    _Pragma("unroll")                                                           \
    for (int dt = 0; dt < 4; ++dt)                                              \
      _Pragma("unroll")                                                         \
      for (int g = 0; g < 4; ++g) {                                             \
        f32x4 v = *(const f32x4*)&buf[(size_t)(g*16 + ln)*68 + dt*16 + quad*4]; \
        o[dt][g][0] += v[0]; o[dt][g][1] += v[1];                               \
        o[dt][g][2] += v[2]; o[dt][g][3] += v[3];                               \
      }                                                                         \
    _Pragma("unroll")                                                           \
    for (int g = 0; g < 4; ++g) lp[g] += buf[64*68 + g*16 + ln];                \
  } while (0)

  if (w == 1) WR_PART();
  __syncthreads();
  if (w == 0) ACC_PART();
  __syncthreads();
  if (w == 2) WR_PART();
  __syncthreads();
  if (w == 0) ACC_PART();
  __syncthreads();
  if (w == 3) WR_PART();
  __syncthreads();
  if (w == 0) ACC_PART();
  __syncthreads();
  if (w == 0) WR_PART();   // publish fully-reduced O^T + l
  __syncthreads();

  // normalized coalesced output: thread -> (q = tid>>2, 16-d chunk)
  {
    const int q  = tid >> 2;
    const int dc = (tid & 3) << 4;
    const float linv = 1.0f / buf[64*68 + q];
    const float* src = &buf[(size_t)q*68 + dc];
    f16x8 o0, o1;
    #pragma unroll
    for (int jj = 0; jj < 8; ++jj) {
      o0[jj] = (f16)(src[jj] * linv);
      o1[jj] = (f16)(src[8 + jj] * linv);
    }
    f16* dst = &ctx[(size_t)(b*T_ + qt*64 + q)*D_ + h*DH_ + dc];
    *(f16x8*)dst       = o0;
    *(f16x8*)(dst + 8) = o1;
  }
  #undef WR_PART
  #undef ACC_PART
}

// ---------------- output projection GEMM + bias: dbuf + XCD swizzle ----------------
__launch_bounds__(256, 2)
__global__ void out_gemm(const f16* __restrict__ ctx, const f16* __restrict__ woT,
                         const float* __restrict__ bo, float* __restrict__ out) {
  const int fid = blockIdx.x;             // [0,256)
  const int g = fid & 7, r = fid >> 3;
  const int m0 = ((((r & 3) << 3) | g)) * 128;   // m-block % 8 == XCD
  const int n0 = (r >> 2) * 128;
  __shared__ alignas(16) f16 smem[4*128*64];     // As[2]|Bs[2]
  f16* AsF = smem;
  f16* BsF = AsF + 2*128*64;
  const int tid = threadIdx.x;
  const int lane = tid & 63, wave = tid >> 6;
  const int ln = lane & 15, quad = lane >> 4;
  const int wm = wave >> 1, wn = wave & 1;

  f32x4 acc[4][4];   // [nt][mt], C^T layout
  #pragma unroll
  for (int a=0;a<4;++a)
    #pragma unroll
    for (int b=0;b<4;++b) acc[a][b] = f32x4{0.f,0.f,0.f,0.f};

  #pragma unroll
  for (int p = 0; p < 4; ++p) {
    int slot = p*256 + tid;
    int row  = slot >> 3;
    int c    = (slot & 7) ^ (row & 7);
    GLOAD_LDS(ctx + (size_t)(m0+row)*D_ + c*8, AsF + (size_t)slot*8);
    GLOAD_LDS(woT + (size_t)(n0+row)*D_ + c*8, BsF + (size_t)slot*8);
  }
  __syncthreads();

  for (int it = 0; it < 16; ++it) {
    const f16* Ac = AsF + (it & 1)*8192;
    const f16* Bc = BsF + (it & 1)*8192;
    if (it < 15) {
      const int k1 = (it + 1) * 64;
      f16* An = AsF + ((it + 1) & 1)*8192;
      f16* Bn = BsF + ((it + 1) & 1)*8192;
      #pragma unroll
      for (int p = 0; p < 4; ++p) {
        int slot = p*256 + tid;
        int row  = slot >> 3;
        int c    = (slot & 7) ^ (row & 7);
        GLOAD_LDS(ctx + (size_t)(m0+row)*D_ + k1 + c*8, An + (size_t)slot*8);
        GLOAD_LDS(woT + (size_t)(n0+row)*D_ + k1 + c*8, Bn + (size_t)slot*8);
      }
    }
    #pragma unroll
    for (int ks = 0; ks < 2; ++ks) {
      const int cb = ((ks*4 + quad) ^ (ln & 7)) * 8;
      f16x8 af[4], bf[4];
      #pragma unroll
      for (int mt = 0; mt < 4; ++mt)
        af[mt] = *(const f16x8*)(Ac + (size_t)(wm*64 + mt*16 + ln)*64 + cb);
      #pragma unroll
      for (int nt = 0; nt < 4; ++nt)
        bf[nt] = *(const f16x8*)(Bc + (size_t)(wn*64 + nt*16 + ln)*64 + cb);
      #pragma unroll
      for (int nt = 0; nt < 4; ++nt)
        #pragma unroll
        for (int mt = 0; mt < 4; ++mt)
          acc[nt][mt] = __builtin_amdgcn_mfma_f32_16x16x32_f16(bf[nt], af[mt], acc[nt][mt], 0, 0, 0);
    }
    __syncthreads();
  }

  #pragma unroll
  for (int nt = 0; nt < 4; ++nt) {
    int gn = n0 + wn*64 + nt*16 + quad*4;
    float4 bv = *(const float4*)&bo[gn];
    #pragma unroll
    for (int mt = 0; mt < 4; ++mt) {
      int gm = m0 + wm*64 + mt*16 + ln;
      float4 v;
      v.x = acc[nt][mt][0] + bv.x;
      v.y = acc[nt][mt][1] + bv.y;
      v.z = acc[nt][mt][2] + bv.z;
      v.w = acc[nt][mt][3] + bv.w;
      *(float4*)&out[(size_t)gm*D_ + gn] = v;
    }
  }
}

extern "C" void kernel_launch(void* const* d_in, const int* in_sizes, int n_in,
                              void* d_out, int out_size, void* d_ws, size_t ws_size,
                              hipStream_t stream) {
  const float* x  = (const float*)d_in[0];
  const float* wq = (const float*)d_in[1];
  const float* wk = (const float*)d_in[2];
  const float* wv = (const float*)d_in[3];
  const float* wo = (const float*)d_in[4];
  const float* bo = (const float*)d_in[5];
  float* out = (float*)d_out;

  f16* ws    = (f16*)d_ws;
  f16* xb    = ws;                         // M_*D_
  f16* wqkvT = xb    + (size_t)M_*D_;      // 3*D_*D_
  f16* woutT = wqkvT + (size_t)3*D_*D_;    // D_*D_
  f16* Qb    = woutT + (size_t)D_*D_;      // M_*D_  ([b,h,t,d], pre-scaled by 0.125*log2e)
  f16* Kb    = Qb    + (size_t)M_*D_;      // M_*D_  ([b,h,t,d])
  f16* Vb    = Kb    + (size_t)M_*D_;      // M_*D_  ([b,h,d,t])
  f16* ctx   = Vb    + (size_t)M_*D_;      // M_*D_  ([b*t, h*d])

  prep<<<6144, 256, 0, stream>>>(x, wq, wk, wv, wo, xb, wqkvT, woutT);
  qkv_gemm<<<192, 512, 0, stream>>>(xb, wqkvT, Qb, Kb, Vb);
  flash<<<1024, 256, 0, stream>>>(Qb, Kb, Vb, ctx);
  out_gemm<<<256, 256, 0, stream>>>(ctx, woutT, bo, out);
}

// Round 6
// 203.192 us; speedup vs baseline: 1.8345x; 1.8345x over previous
//
#include <hip/hip_runtime.h>
#include <hip/hip_bf16.h>

#define B_  2
#define T_  2048
#define D_  1024
#define H_  16
#define DH_ 64
#define M_  (B_*T_)   // 4096

typedef _Float16 f16;
typedef __attribute__((ext_vector_type(4))) _Float16 f16x4;
typedef __attribute__((ext_vector_type(8))) _Float16 f16x8;
typedef __attribute__((ext_vector_type(4))) float f32x4;

// async global->LDS, 16B per lane; LDS dest must be wave-uniform-base + lane*16
#define GLOAD_LDS(gp, lp) __builtin_amdgcn_global_load_lds( \
    (const __attribute__((address_space(1))) void*)(gp),    \
    (__attribute__((address_space(3))) void*)(lp), 16, 0, 0)

// ---------------- prep: x fp32->fp16 convert + 4 weight transposes, one launch ----------------
__global__ void prep(const float* __restrict__ x,
                     const float* __restrict__ wq, const float* __restrict__ wk,
                     const float* __restrict__ wv, const float* __restrict__ wo,
                     f16* __restrict__ xb, f16* __restrict__ wqkvT, f16* __restrict__ woutT) {
  __shared__ float tile[32][33];
  const int bid = blockIdx.x;
  if (bid < 2048) {
    size_t i = ((size_t)bid * 256 + threadIdx.x) * 8;
    float4 a = *(const float4*)(x + i);
    float4 b = *(const float4*)(x + i + 4);
    f16x8 o;
    o[0]=(f16)a.x; o[1]=(f16)a.y; o[2]=(f16)a.z; o[3]=(f16)a.w;
    o[4]=(f16)b.x; o[5]=(f16)b.y; o[6]=(f16)b.z; o[7]=(f16)b.w;
    *(f16x8*)(xb + i) = o;
  } else {
    const int b2 = bid - 2048;
    const int j = b2 >> 10, rem = b2 & 1023;
    const float* src = (j==0)?wq:(j==1)?wk:(j==2)?wv:wo;
    f16* dst = (j<3) ? (wqkvT + (size_t)j*D_*D_) : woutT;
    const int n0 = (rem & 31)*32, k0 = (rem >> 5)*32;
    const int tx = threadIdx.x & 31, ty = threadIdx.x >> 5;  // (32,8)
    #pragma unroll
    for (int i=0;i<32;i+=8)
      tile[ty+i][tx] = src[(size_t)(k0+ty+i)*D_ + n0+tx];
    __syncthreads();
    #pragma unroll
    for (int i=0;i<32;i+=8)
      dst[(size_t)(n0+ty+i)*D_ + k0+tx] = (f16)tile[tx][ty+i];
  }
}

// ---------------- QKV projection GEMM: m97-style single-buffer 2-barrier K-loop ---------------
// 128x128 tile, BK=64, LDS 32 KB (A+B single-buffered) -> 3 blocks/CU co-resident (grid 768,
// launch_bounds(256,3), VGPR ~130 < 168 cap). Cross-block TLP hides the stage drain (m97/m114):
// while one block sits at the vmcnt(0)+barrier, the other two blocks' waves issue MFMA.
__launch_bounds__(256, 3)
__global__ void qkv_gemm(const f16* __restrict__ xb, const f16* __restrict__ wT,
                         f16* __restrict__ Qp, f16* __restrict__ Kp, f16* __restrict__ Vtp) {
  const int fid = blockIdx.x;
  const int g = fid & 7, r = fid >> 3;
  const int m0 = ((((r & 3) << 3) | g)) * 128;   // 32 m-blocks; m-block % 8 == XCD
  const int n0 = ((r >> 2) & 7) * 128;           // 8 n-blocks
  const int j  = r >> 5;                         // 0..2
  const f16* A0 = xb + (size_t)m0 * D_;
  const f16* B0 = wT + (size_t)j * D_ * D_ + (size_t)n0 * D_;
  __shared__ alignas(16) char smem[34816];       // As|Bs = 32 KB; VtS overlay needs 34816 B
  f16* AsF = (f16*)smem;             // [128*64]
  f16* BsF = AsF + 128*64;           // [128*64]
  const int tid = threadIdx.x;
  const int lane = tid & 63, wave = tid >> 6;
  const int ln = lane & 15, quad = lane >> 4;
  const int wm = wave >> 1, wn = wave & 1;

  f32x4 acc[4][4];
  #pragma unroll
  for (int a=0;a<4;++a)
    #pragma unroll
    for (int b=0;b<4;++b) acc[a][b] = f32x4{0.f,0.f,0.f,0.f};

  const bool swapped = (j < 2);

  // stage K-tile tt (cols tt*64..+64) of A and B into the single buffer
  #define STAGE(tt) do {                                                      \
    const int k0_ = (tt)*64;                                                  \
    _Pragma("unroll")                                                         \
    for (int p_ = 0; p_ < 4; ++p_) {                                          \
      int slot_ = p_*256 + tid;                                               \
      int row_  = slot_ >> 3;                                                 \
      int c_    = (slot_ & 7) ^ (row_ & 7);                                   \
      GLOAD_LDS(A0 + (size_t)row_*D_ + k0_ + c_*8, AsF + (size_t)slot_*8);    \
      GLOAD_LDS(B0 + (size_t)row_*D_ + k0_ + c_*8, BsF + (size_t)slot_*8);    \
    }                                                                         \
  } while (0)

  STAGE(0);

  for (int it = 0; it < 16; ++it) {
    __syncthreads();   // drains vmcnt(0): staged tile visible to all waves
    #pragma unroll
    for (int ks = 0; ks < 2; ++ks) {
      const int cb = ((ks*4 + quad) ^ (ln & 7)) * 8;
      f16x8 af[4], bf[4];
      #pragma unroll
      for (int mt = 0; mt < 4; ++mt)
        af[mt] = *(const f16x8*)(AsF + (size_t)(wm*64 + mt*16 + ln)*64 + cb);
      #pragma unroll
      for (int nt = 0; nt < 4; ++nt)
        bf[nt] = *(const f16x8*)(BsF + (size_t)(wn*64 + nt*16 + ln)*64 + cb);
      if (swapped) {
        #pragma unroll
        for (int nt = 0; nt < 4; ++nt)
          #pragma unroll
          for (int mt = 0; mt < 4; ++mt)
            acc[nt][mt] = __builtin_amdgcn_mfma_f32_16x16x32_f16(bf[nt], af[mt], acc[nt][mt], 0, 0, 0);
      } else {
        #pragma unroll
        for (int mt = 0; mt < 4; ++mt)
          #pragma unroll
          for (int nt = 0; nt < 4; ++nt)
            acc[mt][nt] = __builtin_amdgcn_mfma_f32_16x16x32_f16(af[mt], bf[nt], acc[mt][nt], 0, 0, 0);
      }
    }
    __syncthreads();   // all waves done reading this tile
    if (it < 15) STAGE(it + 1);
  }
  #undef STAGE

  if (swapped) {
    // C^T: row n = wn*64+nt*16+quad*4+r (feature), col m = wm*64+mt*16+ln (token)
    // Q pre-scale folds softmax 1/8 AND log2(e) so flash can use exp2 directly.
    const float scale = (j == 0) ? (0.125f * 1.44269504088896f) : 1.0f;
    f16* dstB = (j == 0) ? Qp : Kp;
    #pragma unroll
    for (int nt = 0; nt < 4; ++nt)
      #pragma unroll
      for (int mt = 0; mt < 4; ++mt) {
        int gm = m0 + wm*64 + mt*16 + ln;            // token
        int gn = n0 + wn*64 + nt*16 + quad*4;        // feature (base of 4)
        int bb = gm >> 11, t = gm & (T_-1);
        int h  = gn >> 6,  dd = gn & (DH_-1);
        f16x4 v;
        #pragma unroll
        for (int rr = 0; rr < 4; ++rr) v[rr] = (f16)(acc[nt][mt][rr] * scale);
        *(f16x4*)&dstB[((((size_t)bb*H_ + h)*T_ + t)*DH_) + dd] = v;
      }
  } else {
    // V -> [b,h,d,t] via LDS transpose bounce (coalesced 128B global stores)
    f16* VtS = (f16*)smem;              // [128][136] = 34816 B, safe after final barrier
    #pragma unroll
    for (int mt = 0; mt < 4; ++mt)
      #pragma unroll
      for (int nt = 0; nt < 4; ++nt) {
        f16x4 v;
        v[0]=(f16)acc[mt][nt][0]; v[1]=(f16)acc[mt][nt][1];
        v[2]=(f16)acc[mt][nt][2]; v[3]=(f16)acc[mt][nt][3];
        *(f16x4*)&VtS[(size_t)(wn*64 + nt*16 + ln)*136 + wm*64 + mt*16 + quad*4] = v;
      }
    __syncthreads();
    int dd_loc = tid >> 1, half = tid & 1;
    int gn = n0 + dd_loc, h = gn >> 6, dd = gn & (DH_-1);
    int bb = m0 >> 11, tb = (m0 & (T_-1)) + half*64;
    f16* dst = Vtp + ((size_t)(bb*H_ + h)*DH_ + dd)*T_ + tb;
    const f16* src = VtS + (size_t)dd_loc*136 + half*64;
    #pragma unroll
    for (int u = 0; u < 8; ++u)
      *(uint4*)(dst + u*8) = *(const uint4*)(src + u*8);
  }
}

// ---------------- flash attention v3: kv-split waves, in-register P ----------------
// grid 1024: bh = fid & 31 (same head -> same XCD), qt = 31 - (fid >> 5) (heavy first).
// Block owns ONE 64-row q-tile; wave w owns kv rows [w*16, w*16+16) of each staged tile.
// All 64 q rows in registers (qf[4][2]). S^T fragment (kv=quad*4+rr, q=ln) is EXACTLY the
// B-operand fragment of mfma_f32_16x16x16f16 -> P never touches LDS or lanes.
__launch_bounds__(256, 3)
__global__ void flash(const f16* __restrict__ Qp, const f16* __restrict__ Kp,
                      const f16* __restrict__ Vtp, f16* __restrict__ ctx) {
  const int fid = blockIdx.x;
  const int bh = fid & 31;
  const int qt = 31 - (fid >> 5);       // heavy first
  const int b = bh >> 4, h = bh & (H_-1);
  const f16* Kh = Kp  + (size_t)bh * T_ * DH_;
  const f16* Vh = Vtp + (size_t)bh * DH_ * T_;
  const f16* Qh = Qp  + (size_t)bh * T_ * DH_;
  const int tid = threadIdx.x, lane = tid & 63, w = tid >> 6;
  const int ln = lane & 15, quad = lane >> 4;

  __shared__ alignas(16) char smem[32768];
  f16* Ks = (f16*)smem;            // [2][64][64], XOR-swizzled 16B blocks
  f16* Vs = (f16*)(smem + 16384);  // [2][64][64] (V^T rows d), same swizzle

  // Q fragments: all 64 q rows (4 groups of 16) per wave
  f16x8 qf[4][2];
  #pragma unroll
  for (int g = 0; g < 4; ++g)
    #pragma unroll
    for (int ks = 0; ks < 2; ++ks)
      qf[g][ks] = *(const f16x8*)&Qh[(size_t)(qt*64 + g*16 + ln)*DH_ + ks*32 + quad*8];

  f32x4 o[4][4];   // [dt][g]: O^T[d=dt*16+quad*4+rr][q=g*16+ln] partial over wave's kv
  #pragma unroll
  for (int dt = 0; dt < 4; ++dt)
    #pragma unroll
    for (int g = 0; g < 4; ++g) o[dt][g] = f32x4{0.f,0.f,0.f,0.f};
  float lp[4] = {0.f, 0.f, 0.f, 0.f};

  // prologue: stage kv tile 0 into buffer 0
  #pragma unroll
  for (int i = 0; i < 2; ++i) {
    int slot = i*256 + tid;
    int row  = slot >> 3;
    int c    = (slot & 7) ^ (row & 7);
    GLOAD_LDS(Kh + (size_t)row*DH_ + c*8, Ks + (size_t)slot*8);
    GLOAD_LDS(Vh + (size_t)row*T_  + c*8, Vs + (size_t)slot*8);
  }
  __syncthreads();

  for (int it = 0; it <= qt; ++it) {
    const f16* Kc = Ks + (it & 1)*4096;
    const f16* Vc = Vs + (it & 1)*4096;
    if (it < qt) {    // async-prefetch next tile into other buffer
      const int kv1 = (it + 1)*64;
      f16* Kn = Ks + ((it + 1) & 1)*4096;
      f16* Vn = Vs + ((it + 1) & 1)*4096;
      #pragma unroll
      for (int i = 0; i < 2; ++i) {
        int slot = i*256 + tid;
        int row  = slot >> 3;
        int c    = (slot & 7) ^ (row & 7);
        GLOAD_LDS(Kh + (size_t)(kv1 + row)*DH_ + c*8, Kn + (size_t)slot*8);
        GLOAD_LDS(Vh + (size_t)row*T_ + kv1 + c*8,    Vn + (size_t)slot*8);
      }
    }

    // QK^T: s[g] = S^T[kv = w*16+quad*4+rr][q = g*16+ln]
    f32x4 s[4];
    #pragma unroll
    for (int g = 0; g < 4; ++g) s[g] = f32x4{0.f,0.f,0.f,0.f};
    #pragma unroll
    for (int ks = 0; ks < 2; ++ks) {
      f16x8 kx = *(const f16x8*)(Kc + (size_t)(w*16 + ln)*64 + (((ks*4 + quad) ^ (ln & 7))*8));
      #pragma unroll
      for (int g = 0; g < 4; ++g)
        s[g] = __builtin_amdgcn_mfma_f32_16x16x32_f16(kx, qf[g][ks], s[g], 0, 0, 0);
    }

    if (it == qt) {    // diagonal tile: causal mask (kv_local > q_local)
      #pragma unroll
      for (int g = 0; g < 4; ++g)
        #pragma unroll
        for (int rr = 0; rr < 4; ++rr)
          if (w*16 + quad*4 + rr > g*16 + ln) s[g][rr] = -INFINITY;
    }

    // exp2 (Q pre-scaled by log2e) + pack to f16 + denominator partials
    f16x4 pb[4];
    #pragma unroll
    for (int g = 0; g < 4; ++g) {
      #pragma unroll
      for (int rr = 0; rr < 4; ++rr) {
        float pe = __builtin_amdgcn_exp2f(s[g][rr]);
        lp[g] += pe;
        pb[g][rr] = (f16)pe;
      }
    }

    // PV partial: o[dt][g] += V^T[d][kv-slice] * P^T[kv-slice][q], k=16 MFMA
    #pragma unroll
    for (int dt = 0; dt < 4; ++dt) {
      f16x4 vf = *(const f16x4*)(Vc + (size_t)(dt*16 + ln)*64
                   + (((2*w + (quad >> 1)) ^ (ln & 7))*8) + (quad & 1)*4);
      #pragma unroll
      for (int g = 0; g < 4; ++g)
        o[dt][g] = __builtin_amdgcn_mfma_f32_16x16x16f16(vf, pb[g], o[dt][g], 0, 0, 0);
    }
    __syncthreads();   // drains vmcnt(0): prefetched tile complete; bufs safe to swap
  }

  // quad-reduce denominator partials (each lane's lp covers its quad's 4 kv rows)
  #pragma unroll
  for (int g = 0; g < 4; ++g) {
    lp[g] += __shfl_xor(lp[g], 16, 64);
    lp[g] += __shfl_xor(lp[g], 32, 64);
  }

  // cross-wave reduction tree in LDS (reuse Ks/Vs region): buf[65][68] f32 (O^T rows 0..63, l row 64)
  float* buf = (float*)smem;
  #define WR_PART() do {                                                        \
    _Pragma("unroll")                                                           \
    for (int dt = 0; dt < 4; ++dt)                                              \
      _Pragma("unroll")                                                         \
      for (int g = 0; g < 4; ++g)                                               \
        *(f32x4*)&buf[(size_t)(g*16 + ln)*68 + dt*16 + quad*4] = o[dt][g];      \
    if (quad == 0) {                                                            \
      _Pragma("unroll")                                                         \
      for (int g = 0; g < 4; ++g) buf[64*68 + g*16 + ln] = lp[g];               \
    }                                                                           \
  } while (0)
  #define ACC_PART() do {                                                       \
    _Pragma("unroll")                                                           \
    for (int dt = 0; dt < 4; ++dt)                                              \
      _Pragma("unroll")                                                         \
      for (int g = 0; g < 4; ++g) {                                             \
        f32x4 v = *(const f32x4*)&buf[(size_t)(g*16 + ln)*68 + dt*16 + quad*4]; \
        o[dt][g][0] += v[0]; o[dt][g][1] += v[1];                               \
        o[dt][g][2] += v[2]; o[dt][g][3] += v[3];                               \
      }                                                                         \
    _Pragma("unroll")                                                           \
    for (int g = 0; g < 4; ++g) lp[g] += buf[64*68 + g*16 + ln];                \
  } while (0)

  if (w == 1) WR_PART();
  __syncthreads();
  if (w == 0) ACC_PART();
  __syncthreads();
  if (w == 2) WR_PART();
  __syncthreads();
  if (w == 0) ACC_PART();
  __syncthreads();
  if (w == 3) WR_PART();
  __syncthreads();
  if (w == 0) ACC_PART();
  __syncthreads();
  if (w == 0) WR_PART();   // publish fully-reduced O^T + l
  __syncthreads();

  // normalized coalesced output: thread -> (q = tid>>2, 16-d chunk)
  {
    const int q  = tid >> 2;
    const int dc = (tid & 3) << 4;
    const float linv = 1.0f / buf[64*68 + q];
    const float* src = &buf[(size_t)q*68 + dc];
    f16x8 o0, o1;
    #pragma unroll
    for (int jj = 0; jj < 8; ++jj) {
      o0[jj] = (f16)(src[jj] * linv);
      o1[jj] = (f16)(src[8 + jj] * linv);
    }
    f16* dst = &ctx[(size_t)(b*T_ + qt*64 + q)*D_ + h*DH_ + dc];
    *(f16x8*)dst       = o0;
    *(f16x8*)(dst + 8) = o1;
  }
  #undef WR_PART
  #undef ACC_PART
}

// ---------------- output projection GEMM + bias: dbuf + XCD swizzle ----------------
__launch_bounds__(256, 2)
__global__ void out_gemm(const f16* __restrict__ ctx, const f16* __restrict__ woT,
                         const float* __restrict__ bo, float* __restrict__ out) {
  const int fid = blockIdx.x;             // [0,256)
  const int g = fid & 7, r = fid >> 3;
  const int m0 = ((((r & 3) << 3) | g)) * 128;   // m-block % 8 == XCD
  const int n0 = (r >> 2) * 128;
  __shared__ alignas(16) f16 smem[4*128*64];     // As[2]|Bs[2]
  f16* AsF = smem;
  f16* BsF = AsF + 2*128*64;
  const int tid = threadIdx.x;
  const int lane = tid & 63, wave = tid >> 6;
  const int ln = lane & 15, quad = lane >> 4;
  const int wm = wave >> 1, wn = wave & 1;

  f32x4 acc[4][4];   // [nt][mt], C^T layout
  #pragma unroll
  for (int a=0;a<4;++a)
    #pragma unroll
    for (int b=0;b<4;++b) acc[a][b] = f32x4{0.f,0.f,0.f,0.f};

  #pragma unroll
  for (int p = 0; p < 4; ++p) {
    int slot = p*256 + tid;
    int row  = slot >> 3;
    int c    = (slot & 7) ^ (row & 7);
    GLOAD_LDS(ctx + (size_t)(m0+row)*D_ + c*8, AsF + (size_t)slot*8);
    GLOAD_LDS(woT + (size_t)(n0+row)*D_ + c*8, BsF + (size_t)slot*8);
  }
  __syncthreads();

  for (int it = 0; it < 16; ++it) {
    const f16* Ac = AsF + (it & 1)*8192;
    const f16* Bc = BsF + (it & 1)*8192;
    if (it < 15) {
      const int k1 = (it + 1) * 64;
      f16* An = AsF + ((it + 1) & 1)*8192;
      f16* Bn = BsF + ((it + 1) & 1)*8192;
      #pragma unroll
      for (int p = 0; p < 4; ++p) {
        int slot = p*256 + tid;
        int row  = slot >> 3;
        int c    = (slot & 7) ^ (row & 7);
        GLOAD_LDS(ctx + (size_t)(m0+row)*D_ + k1 + c*8, An + (size_t)slot*8);
        GLOAD_LDS(woT + (size_t)(n0+row)*D_ + k1 + c*8, Bn + (size_t)slot*8);
      }
    }
    #pragma unroll
    for (int ks = 0; ks < 2; ++ks) {
      const int cb = ((ks*4 + quad) ^ (ln & 7)) * 8;
      f16x8 af[4], bf[4];
      #pragma unroll
      for (int mt = 0; mt < 4; ++mt)
        af[mt] = *(const f16x8*)(Ac + (size_t)(wm*64 + mt*16 + ln)*64 + cb);
      #pragma unroll
      for (int nt = 0; nt < 4; ++nt)
        bf[nt] = *(const f16x8*)(Bc + (size_t)(wn*64 + nt*16 + ln)*64 + cb);
      #pragma unroll
      for (int nt = 0; nt < 4; ++nt)
        #pragma unroll
        for (int mt = 0; mt < 4; ++mt)
          acc[nt][mt] = __builtin_amdgcn_mfma_f32_16x16x32_f16(bf[nt], af[mt], acc[nt][mt], 0, 0, 0);
    }
    __syncthreads();
  }

  #pragma unroll
  for (int nt = 0; nt < 4; ++nt) {
    int gn = n0 + wn*64 + nt*16 + quad*4;
    float4 bv = *(const float4*)&bo[gn];
    #pragma unroll
    for (int mt = 0; mt < 4; ++mt) {
      int gm = m0 + wm*64 + mt*16 + ln;
      float4 v;
      v.x = acc[nt][mt][0] + bv.x;
      v.y = acc[nt][mt][1] + bv.y;
      v.z = acc[nt][mt][2] + bv.z;
      v.w = acc[nt][mt][3] + bv.w;
      *(float4*)&out[(size_t)gm*D_ + gn] = v;
    }
  }
}

extern "C" void kernel_launch(void* const* d_in, const int* in_sizes, int n_in,
                              void* d_out, int out_size, void* d_ws, size_t ws_size,
                              hipStream_t stream) {
  const float* x  = (const float*)d_in[0];
  const float* wq = (const float*)d_in[1];
  const float* wk = (const float*)d_in[2];
  const float* wv = (const float*)d_in[3];
  const float* wo = (const float*)d_in[4];
  const float* bo = (const float*)d_in[5];
  float* out = (float*)d_out;

  f16* ws    = (f16*)d_ws;
  f16* xb    = ws;                         // M_*D_
  f16* wqkvT = xb    + (size_t)M_*D_;      // 3*D_*D_
  f16* woutT = wqkvT + (size_t)3*D_*D_;    // D_*D_
  f16* Qb    = woutT + (size_t)D_*D_;      // M_*D_  ([b,h,t,d], pre-scaled by 0.125*log2e)
  f16* Kb    = Qb    + (size_t)M_*D_;      // M_*D_  ([b,h,t,d])
  f16* Vb    = Kb    + (size_t)M_*D_;      // M_*D_  ([b,h,d,t])
  f16* ctx   = Vb    + (size_t)M_*D_;      // M_*D_  ([b*t, h*d])

  prep<<<6144, 256, 0, stream>>>(x, wq, wk, wv, wo, xb, wqkvT, woutT);
  qkv_gemm<<<768, 256, 0, stream>>>(xb, wqkvT, Qb, Kb, Vb);
  flash<<<1024, 256, 0, stream>>>(Qb, Kb, Vb, ctx);
  out_gemm<<<256, 256, 0, stream>>>(ctx, woutT, bo, out);
}

// Round 7
// 163.881 us; speedup vs baseline: 2.2745x; 1.2399x over previous
//
#include <hip/hip_runtime.h>
#include <hip/hip_bf16.h>

#define B_  2
#define T_  2048
#define D_  1024
#define H_  16
#define DH_ 64
#define M_  (B_*T_)   // 4096

typedef _Float16 f16;
typedef __attribute__((ext_vector_type(4))) _Float16 f16x4;
typedef __attribute__((ext_vector_type(8))) _Float16 f16x8;
typedef __attribute__((ext_vector_type(4))) float f32x4;

// async global->LDS, 16B per lane; LDS dest must be wave-uniform-base + lane*16
#define GLOAD_LDS(gp, lp) __builtin_amdgcn_global_load_lds( \
    (const __attribute__((address_space(1))) void*)(gp),    \
    (__attribute__((address_space(3))) void*)(lp), 16, 0, 0)

// ---------------- prep: x fp32->fp16 convert + 4 weight transposes, one launch ----------------
__global__ void prep(const float* __restrict__ x,
                     const float* __restrict__ wq, const float* __restrict__ wk,
                     const float* __restrict__ wv, const float* __restrict__ wo,
                     f16* __restrict__ xb, f16* __restrict__ wqkvT, f16* __restrict__ woutT) {
  __shared__ float tile[32][33];
  const int bid = blockIdx.x;
  if (bid < 2048) {
    size_t i = ((size_t)bid * 256 + threadIdx.x) * 8;
    float4 a = *(const float4*)(x + i);
    float4 b = *(const float4*)(x + i + 4);
    f16x8 o;
    o[0]=(f16)a.x; o[1]=(f16)a.y; o[2]=(f16)a.z; o[3]=(f16)a.w;
    o[4]=(f16)b.x; o[5]=(f16)b.y; o[6]=(f16)b.z; o[7]=(f16)b.w;
    *(f16x8*)(xb + i) = o;
  } else {
    const int b2 = bid - 2048;
    const int j = b2 >> 10, rem = b2 & 1023;
    const float* src = (j==0)?wq:(j==1)?wk:(j==2)?wv:wo;
    f16* dst = (j<3) ? (wqkvT + (size_t)j*D_*D_) : woutT;
    const int n0 = (rem & 31)*32, k0 = (rem >> 5)*32;
    const int tx = threadIdx.x & 31, ty = threadIdx.x >> 5;  // (32,8)
    #pragma unroll
    for (int i=0;i<32;i+=8)
      tile[ty+i][tx] = src[(size_t)(k0+ty+i)*D_ + n0+tx];
    __syncthreads();
    #pragma unroll
    for (int i=0;i<32;i+=8)
      dst[(size_t)(n0+ty+i)*D_ + k0+tx] = (f16)tile[tx][ty+i];
  }
}

// ---------------- QKV projection GEMM: dbuf K-loop + XCD swizzle (round-3 proven, ~31 us) -----
__launch_bounds__(256, 2)
__global__ void qkv_gemm(const f16* __restrict__ xb, const f16* __restrict__ wT,
                         f16* __restrict__ Qp, f16* __restrict__ Kp, f16* __restrict__ Vtp) {
  const int fid = blockIdx.x;
  const int g = fid & 7, r = fid >> 3;
  const int m0 = ((((r & 3) << 3) | g)) * 128;   // 32 m-blocks; m-block % 8 == XCD
  const int n0 = ((r >> 2) & 7) * 128;           // 8 n-blocks
  const int j  = r >> 5;                         // 0..2
  const f16* B0 = wT + (size_t)j * D_ * D_;
  __shared__ alignas(16) char smem[65536];       // As[2]|Bs[2] = 64 KB; VtS reuses front
  f16* AsF = (f16*)smem;             // [2][128*64]
  f16* BsF = AsF + 2*128*64;         // [2][128*64]
  const int tid = threadIdx.x;
  const int lane = tid & 63, wave = tid >> 6;
  const int ln = lane & 15, quad = lane >> 4;
  const int wm = wave >> 1, wn = wave & 1;

  f32x4 acc[4][4];
  #pragma unroll
  for (int a=0;a<4;++a)
    #pragma unroll
    for (int b=0;b<4;++b) acc[a][b] = f32x4{0.f,0.f,0.f,0.f};

  const bool swapped = (j < 2);
  const int slot_row[4] = { (0*256+tid)>>3, (1*256+tid)>>3, (2*256+tid)>>3, (3*256+tid)>>3 };

  #pragma unroll
  for (int p = 0; p < 4; ++p) {
    int slot = p*256 + tid;
    int row  = slot_row[p];
    int c    = (slot & 7) ^ (row & 7);
    GLOAD_LDS(xb + (size_t)(m0+row)*D_ + c*8, AsF + (size_t)slot*8);
    GLOAD_LDS(B0 + (size_t)(n0+row)*D_ + c*8, BsF + (size_t)slot*8);
  }
  __syncthreads();

  for (int it = 0; it < 16; ++it) {
    const f16* Ac = AsF + (it & 1)*8192;
    const f16* Bc = BsF + (it & 1)*8192;
    if (it < 15) {   // async-prefetch next k-tile into other buffer
      const int k1 = (it + 1) * 64;
      f16* An = AsF + ((it + 1) & 1)*8192;
      f16* Bn = BsF + ((it + 1) & 1)*8192;
      #pragma unroll
      for (int p = 0; p < 4; ++p) {
        int slot = p*256 + tid;
        int row  = slot_row[p];
        int c    = (slot & 7) ^ (row & 7);
        GLOAD_LDS(xb + (size_t)(m0+row)*D_ + k1 + c*8, An + (size_t)slot*8);
        GLOAD_LDS(B0 + (size_t)(n0+row)*D_ + k1 + c*8, Bn + (size_t)slot*8);
      }
    }
    #pragma unroll
    for (int ks = 0; ks < 2; ++ks) {
      const int cb = ((ks*4 + quad) ^ (ln & 7)) * 8;
      f16x8 af[4], bf[4];
      #pragma unroll
      for (int mt = 0; mt < 4; ++mt)
        af[mt] = *(const f16x8*)(Ac + (size_t)(wm*64 + mt*16 + ln)*64 + cb);
      #pragma unroll
      for (int nt = 0; nt < 4; ++nt)
        bf[nt] = *(const f16x8*)(Bc + (size_t)(wn*64 + nt*16 + ln)*64 + cb);
      if (swapped) {
        #pragma unroll
        for (int nt = 0; nt < 4; ++nt)
          #pragma unroll
          for (int mt = 0; mt < 4; ++mt)
            acc[nt][mt] = __builtin_amdgcn_mfma_f32_16x16x32_f16(bf[nt], af[mt], acc[nt][mt], 0, 0, 0);
      } else {
        #pragma unroll
        for (int mt = 0; mt < 4; ++mt)
          #pragma unroll
          for (int nt = 0; nt < 4; ++nt)
            acc[mt][nt] = __builtin_amdgcn_mfma_f32_16x16x32_f16(af[mt], bf[nt], acc[mt][nt], 0, 0, 0);
      }
    }
    __syncthreads();   // drains vmcnt(0): prefetch done; all reads of Ac/Bc done
  }

  if (swapped) {
    // C^T: row n = wn*64+nt*16+quad*4+r (feature), col m = wm*64+mt*16+ln (token)
    // Q pre-scale folds softmax 1/8 AND log2(e) so flash can use exp2 directly.
    const float scale = (j == 0) ? (0.125f * 1.44269504088896f) : 1.0f;
    f16* dstB = (j == 0) ? Qp : Kp;
    #pragma unroll
    for (int nt = 0; nt < 4; ++nt)
      #pragma unroll
      for (int mt = 0; mt < 4; ++mt) {
        int gm = m0 + wm*64 + mt*16 + ln;            // token
        int gn = n0 + wn*64 + nt*16 + quad*4;        // feature (base of 4)
        int bb = gm >> 11, t = gm & (T_-1);
        int h  = gn >> 6,  dd = gn & (DH_-1);
        f16x4 v;
        #pragma unroll
        for (int rr = 0; rr < 4; ++rr) v[rr] = (f16)(acc[nt][mt][rr] * scale);
        *(f16x4*)&dstB[((((size_t)bb*H_ + h)*T_ + t)*DH_) + dd] = v;
      }
  } else {
    // V -> [b,h,d,t] via LDS transpose bounce (coalesced 128B global stores)
    f16* VtS = (f16*)smem;              // [128][136] = 34816 B, safe after final barrier
    #pragma unroll
    for (int mt = 0; mt < 4; ++mt)
      #pragma unroll
      for (int nt = 0; nt < 4; ++nt) {
        f16x4 v;
        v[0]=(f16)acc[mt][nt][0]; v[1]=(f16)acc[mt][nt][1];
        v[2]=(f16)acc[mt][nt][2]; v[3]=(f16)acc[mt][nt][3];
        *(f16x4*)&VtS[(size_t)(wn*64 + nt*16 + ln)*136 + wm*64 + mt*16 + quad*4] = v;
      }
    __syncthreads();
    int dd_loc = tid >> 1, half = tid & 1;
    int gn = n0 + dd_loc, h = gn >> 6, dd = gn & (DH_-1);
    int bb = m0 >> 11, tb = (m0 & (T_-1)) + half*64;
    f16* dst = Vtp + ((size_t)(bb*H_ + h)*DH_ + dd)*T_ + tb;
    const f16* src = VtS + (size_t)dd_loc*136 + half*64;
    #pragma unroll
    for (int u = 0; u < 8; ++u)
      *(uint4*)(dst + u*8) = *(const uint4*)(src + u*8);
  }
}

// ---------------- flash attention v5: kv-split waves, in-register P, Q in LDS -----------------
// grid 1024: bh = fid & 31 (same head -> same XCD), qt = 31 - (fid >> 5).
// Same as round-3 v3 except the 32 loop-invariant qf VGPRs move to LDS (Qs, 8 KB) and are
// re-read per iteration (same swizzle/bank pattern as kx). VGPR ~118 -> launch_bounds(256,4)
// gives 4 blocks/CU (LDS 40 KB also allows 4): grid 1024 = exactly one full resident pass.
__launch_bounds__(256, 4)
__global__ void flash(const f16* __restrict__ Qp, const f16* __restrict__ Kp,
                      const f16* __restrict__ Vtp, f16* __restrict__ ctx) {
  const int fid = blockIdx.x;
  const int bh = fid & 31;
  const int qt = 31 - (fid >> 5);       // heavy first
  const int b = bh >> 4, h = bh & (H_-1);
  const f16* Kh = Kp  + (size_t)bh * T_ * DH_;
  const f16* Vh = Vtp + (size_t)bh * DH_ * T_;
  const f16* Qh = Qp  + (size_t)bh * T_ * DH_;
  const int tid = threadIdx.x, lane = tid & 63, w = tid >> 6;
  const int ln = lane & 15, quad = lane >> 4;

  __shared__ alignas(16) char smem[40960];
  f16* Ks = (f16*)smem;            // [2][64][64], XOR-swizzled 16B blocks
  f16* Vs = (f16*)(smem + 16384);  // [2][64][64] (V^T rows d), same swizzle
  f16* Qs = (f16*)(smem + 32768);  // [64][64] q-tile, same swizzle (loop-invariant)

  // prologue: stage Q tile + kv tile 0
  #pragma unroll
  for (int i = 0; i < 2; ++i) {
    int slot = i*256 + tid;
    int row  = slot >> 3;
    int c    = (slot & 7) ^ (row & 7);
    GLOAD_LDS(Qh + (size_t)(qt*64 + row)*DH_ + c*8, Qs + (size_t)slot*8);
    GLOAD_LDS(Kh + (size_t)row*DH_ + c*8, Ks + (size_t)slot*8);
    GLOAD_LDS(Vh + (size_t)row*T_  + c*8, Vs + (size_t)slot*8);
  }
  __syncthreads();

  f32x4 o[4][4];   // [dt][g]: O^T[d=dt*16+quad*4+rr][q=g*16+ln] partial over wave's kv
  #pragma unroll
  for (int dt = 0; dt < 4; ++dt)
    #pragma unroll
    for (int g = 0; g < 4; ++g) o[dt][g] = f32x4{0.f,0.f,0.f,0.f};
  float lp[4] = {0.f, 0.f, 0.f, 0.f};

  for (int it = 0; it <= qt; ++it) {
    const f16* Kc = Ks + (it & 1)*4096;
    const f16* Vc = Vs + (it & 1)*4096;
    if (it < qt) {    // async-prefetch next tile into other buffer
      const int kv1 = (it + 1)*64;
      f16* Kn = Ks + ((it + 1) & 1)*4096;
      f16* Vn = Vs + ((it + 1) & 1)*4096;
      #pragma unroll
      for (int i = 0; i < 2; ++i) {
        int slot = i*256 + tid;
        int row  = slot >> 3;
        int c    = (slot & 7) ^ (row & 7);
        GLOAD_LDS(Kh + (size_t)(kv1 + row)*DH_ + c*8, Kn + (size_t)slot*8);
        GLOAD_LDS(Vh + (size_t)row*T_ + kv1 + c*8,    Vn + (size_t)slot*8);
      }
    }

    // QK^T: s[g] = S^T[kv = w*16+quad*4+rr][q = g*16+ln]; qf re-read from LDS per ks
    f32x4 s[4];
    #pragma unroll
    for (int g = 0; g < 4; ++g) s[g] = f32x4{0.f,0.f,0.f,0.f};
    #pragma unroll
    for (int ks = 0; ks < 2; ++ks) {
      const int cb = ((ks*4 + quad) ^ (ln & 7)) * 8;
      f16x8 kx = *(const f16x8*)(Kc + (size_t)(w*16 + ln)*64 + cb);
      #pragma unroll
      for (int g = 0; g < 4; ++g) {
        f16x8 qf = *(const f16x8*)(Qs + (size_t)(g*16 + ln)*64 + cb);
        s[g] = __builtin_amdgcn_mfma_f32_16x16x32_f16(kx, qf, s[g], 0, 0, 0);
      }
    }

    if (it == qt) {    // diagonal tile: causal mask (kv_local > q_local)
      #pragma unroll
      for (int g = 0; g < 4; ++g)
        #pragma unroll
        for (int rr = 0; rr < 4; ++rr)
          if (w*16 + quad*4 + rr > g*16 + ln) s[g][rr] = -INFINITY;
    }

    // exp2 (Q pre-scaled by log2e) + pack to f16 + denominator partials
    f16x4 pb[4];
    #pragma unroll
    for (int g = 0; g < 4; ++g) {
      #pragma unroll
      for (int rr = 0; rr < 4; ++rr) {
        float pe = __builtin_amdgcn_exp2f(s[g][rr]);
        lp[g] += pe;
        pb[g][rr] = (f16)pe;
      }
    }

    // PV partial: o[dt][g] += V^T[d][kv-slice] * P^T[kv-slice][q], k=16 MFMA
    #pragma unroll
    for (int dt = 0; dt < 4; ++dt) {
      f16x4 vf = *(const f16x4*)(Vc + (size_t)(dt*16 + ln)*64
                   + (((2*w + (quad >> 1)) ^ (ln & 7))*8) + (quad & 1)*4);
      #pragma unroll
      for (int g = 0; g < 4; ++g)
        o[dt][g] = __builtin_amdgcn_mfma_f32_16x16x16f16(vf, pb[g], o[dt][g], 0, 0, 0);
    }
    __syncthreads();   // drains vmcnt(0): prefetched tile complete; bufs safe to swap
  }

  // quad-reduce denominator partials (each lane's lp covers its quad's 4 kv rows)
  #pragma unroll
  for (int g = 0; g < 4; ++g) {
    lp[g] += __shfl_xor(lp[g], 16, 64);
    lp[g] += __shfl_xor(lp[g], 32, 64);
  }

  // cross-wave reduction tree in LDS (reuse Ks/Vs region): buf[65][68] f32 (O^T rows 0..63, l row 64)
  float* buf = (float*)smem;
  #define WR_PART() do {                                                        \
    _Pragma("unroll")                                                           \
    for (int dt = 0; dt < 4; ++dt)                                              \
      _Pragma("unroll")                                                         \
      for (int g = 0; g < 4; ++g)                                               \
        *(f32x4*)&buf[(size_t)(g*16 + ln)*68 + dt*16 + quad*4] = o[dt][g];      \
    if (quad == 0) {                                                            \
      _Pragma("unroll")                                                         \
      for (int g = 0; g < 4; ++g) buf[64*68 + g*16 + ln] = lp[g];               \
    }                                                                           \
  } while (0)
  #define ACC_PART() do {                                                       \
    _Pragma("unroll")                                                           \
    for (int dt = 0; dt < 4; ++dt)                                              \
      _Pragma("unroll")                                                         \
      for (int g = 0; g < 4; ++g) {                                             \
        f32x4 v = *(const f32x4*)&buf[(size_t)(g*16 + ln)*68 + dt*16 + quad*4]; \
        o[dt][g][0] += v[0]; o[dt][g][1] += v[1];                               \
        o[dt][g][2] += v[2]; o[dt][g][3] += v[3];                               \
      }                                                                         \
    _Pragma("unroll")                                                           \
    for (int g = 0; g < 4; ++g) lp[g] += buf[64*68 + g*16 + ln];                \
  } while (0)

  if (w == 1) WR_PART();
  __syncthreads();
  if (w == 0) ACC_PART();
  __syncthreads();
  if (w == 2) WR_PART();
  __syncthreads();
  if (w == 0) ACC_PART();
  __syncthreads();
  if (w == 3) WR_PART();
  __syncthreads();
  if (w == 0) ACC_PART();
  __syncthreads();
  if (w == 0) WR_PART();   // publish fully-reduced O^T + l
  __syncthreads();

  // normalized coalesced output: thread -> (q = tid>>2, 16-d chunk)
  {
    const int q  = tid >> 2;
    const int dc = (tid & 3) << 4;
    const float linv = 1.0f / buf[64*68 + q];
    const float* src = &buf[(size_t)q*68 + dc];
    f16x8 o0, o1;
    #pragma unroll
    for (int jj = 0; jj < 8; ++jj) {
      o0[jj] = (f16)(src[jj] * linv);
      o1[jj] = (f16)(src[8 + jj] * linv);
    }
    f16* dst = &ctx[(size_t)(b*T_ + qt*64 + q)*D_ + h*DH_ + dc];
    *(f16x8*)dst       = o0;
    *(f16x8*)(dst + 8) = o1;
  }
  #undef WR_PART
  #undef ACC_PART
}

// ---------------- output projection GEMM + bias: dbuf + XCD swizzle ----------------
__launch_bounds__(256, 2)
__global__ void out_gemm(const f16* __restrict__ ctx, const f16* __restrict__ woT,
                         const float* __restrict__ bo, float* __restrict__ out) {
  const int fid = blockIdx.x;             // [0,256)
  const int g = fid & 7, r = fid >> 3;
  const int m0 = ((((r & 3) << 3) | g)) * 128;   // m-block % 8 == XCD
  const int n0 = (r >> 2) * 128;
  __shared__ alignas(16) f16 smem[4*128*64];     // As[2]|Bs[2]
  f16* AsF = smem;
  f16* BsF = AsF + 2*128*64;
  const int tid = threadIdx.x;
  const int lane = tid & 63, wave = tid >> 6;
  const int ln = lane & 15, quad = lane >> 4;
  const int wm = wave >> 1, wn = wave & 1;

  f32x4 acc[4][4];   // [nt][mt], C^T layout
  #pragma unroll
  for (int a=0;a<4;++a)
    #pragma unroll
    for (int b=0;b<4;++b) acc[a][b] = f32x4{0.f,0.f,0.f,0.f};

  #pragma unroll
  for (int p = 0; p < 4; ++p) {
    int slot = p*256 + tid;
    int row  = slot >> 3;
    int c    = (slot & 7) ^ (row & 7);
    GLOAD_LDS(ctx + (size_t)(m0+row)*D_ + c*8, AsF + (size_t)slot*8);
    GLOAD_LDS(woT + (size_t)(n0+row)*D_ + c*8, BsF + (size_t)slot*8);
  }
  __syncthreads();

  for (int it = 0; it < 16; ++it) {
    const f16* Ac = AsF + (it & 1)*8192;
    const f16* Bc = BsF + (it & 1)*8192;
    if (it < 15) {
      const int k1 = (it + 1) * 64;
      f16* An = AsF + ((it + 1) & 1)*8192;
      f16* Bn = BsF + ((it + 1) & 1)*8192;
      #pragma unroll
      for (int p = 0; p < 4; ++p) {
        int slot = p*256 + tid;
        int row  = slot >> 3;
        int c    = (slot & 7) ^ (row & 7);
        GLOAD_LDS(ctx + (size_t)(m0+row)*D_ + k1 + c*8, An + (size_t)slot*8);
        GLOAD_LDS(woT + (size_t)(n0+row)*D_ + k1 + c*8, Bn + (size_t)slot*8);
      }
    }
    #pragma unroll
    for (int ks = 0; ks < 2; ++ks) {
      const int cb = ((ks*4 + quad) ^ (ln & 7)) * 8;
      f16x8 af[4], bf[4];
      #pragma unroll
      for (int mt = 0; mt < 4; ++mt)
        af[mt] = *(const f16x8*)(Ac + (size_t)(wm*64 + mt*16 + ln)*64 + cb);
      #pragma unroll
      for (int nt = 0; nt < 4; ++nt)
        bf[nt] = *(const f16x8*)(Bc + (size_t)(wn*64 + nt*16 + ln)*64 + cb);
      #pragma unroll
      for (int nt = 0; nt < 4; ++nt)
        #pragma unroll
        for (int mt = 0; mt < 4; ++mt)
          acc[nt][mt] = __builtin_amdgcn_mfma_f32_16x16x32_f16(bf[nt], af[mt], acc[nt][mt], 0, 0, 0);
    }
    __syncthreads();
  }

  #pragma unroll
  for (int nt = 0; nt < 4; ++nt) {
    int gn = n0 + wn*64 + nt*16 + quad*4;
    float4 bv = *(const float4*)&bo[gn];
    #pragma unroll
    for (int mt = 0; mt < 4; ++mt) {
      int gm = m0 + wm*64 + mt*16 + ln;
      float4 v;
      v.x = acc[nt][mt][0] + bv.x;
      v.y = acc[nt][mt][1] + bv.y;
      v.z = acc[nt][mt][2] + bv.z;
      v.w = acc[nt][mt][3] + bv.w;
      *(float4*)&out[(size_t)gm*D_ + gn] = v;
    }
  }
}

extern "C" void kernel_launch(void* const* d_in, const int* in_sizes, int n_in,
                              void* d_out, int out_size, void* d_ws, size_t ws_size,
                              hipStream_t stream) {
  const float* x  = (const float*)d_in[0];
  const float* wq = (const float*)d_in[1];
  const float* wk = (const float*)d_in[2];
  const float* wv = (const float*)d_in[3];
  const float* wo = (const float*)d_in[4];
  const float* bo = (const float*)d_in[5];
  float* out = (float*)d_out;

  f16* ws    = (f16*)d_ws;
  f16* xb    = ws;                         // M_*D_
  f16* wqkvT = xb    + (size_t)M_*D_;      // 3*D_*D_
  f16* woutT = wqkvT + (size_t)3*D_*D_;    // D_*D_
  f16* Qb    = woutT + (size_t)D_*D_;      // M_*D_  ([b,h,t,d], pre-scaled by 0.125*log2e)
  f16* Kb    = Qb    + (size_t)M_*D_;      // M_*D_  ([b,h,t,d])
  f16* Vb    = Kb    + (size_t)M_*D_;      // M_*D_  ([b,h,d,t])
  f16* ctx   = Vb    + (size_t)M_*D_;      // M_*D_  ([b*t, h*d])

  prep<<<6144, 256, 0, stream>>>(x, wq, wk, wv, wo, xb, wqkvT, woutT);
  qkv_gemm<<<768, 256, 0, stream>>>(xb, wqkvT, Qb, Kb, Vb);
  flash<<<1024, 256, 0, stream>>>(Qb, Kb, Vb, ctx);
  out_gemm<<<256, 256, 0, stream>>>(ctx, woutT, bo, out);
}